// Round 1
// baseline (1645.628 us; speedup 1.0000x reference)
//
#include <hip/hip_runtime.h>
#include <cstdint>
#include <cstddef>

// RIMCell forward, MI355X. Pipeline:
//  wtrans: fp32 weights -> f16, transposed to (N,K) row-major, padded (zero) to tile sizes
//  fp32:   kx = x@Wk, q = hs@Wq  (top-k critical -> fp32)
//  f16 MFMA: vx = x@Wv; preact = [a*vx|hs]@[Wi2h;Wh2h]; [cv|ck|cq] = h@[Wcv|Wck|Wcq]; ctxW = ctx@Wco
//  elementwise: s0/mask/alpha, inputs build, LSTM, comm-attention, epilogue.
// Output d_out = [hs_out (B,6,600) | cs_out (B,6,600)] fp32.

typedef _Float16 f16;
typedef _Float16 f16x8 __attribute__((ext_vector_type(8)));
typedef float    f32x4 __attribute__((ext_vector_type(4)));

__device__ __forceinline__ void async16(const void* g, void* l) {
    __builtin_amdgcn_global_load_lds((const __attribute__((address_space(1))) void*)g,
                                     (__attribute__((address_space(3))) void*)l,
                                     16, 0, 0);
}

// ---------------- MFMA f16 GEMM: C[M,N] = A[M,K] * W^T where W stored (N,K) ----
// M%128==0 (grid.x=M/128), N%128==0 (grid.y=N/128), K%32==0. W row pitch == K.
__global__ __launch_bounds__(256)
void mfma_gemm(const f16* __restrict__ A, const f16* __restrict__ W,
               float* __restrict__ C, int K, int lda, int ldc,
               long sAu, long sWu, long sCu)
{
    A += (long)blockIdx.z * sAu;
    W += (long)blockIdx.z * sWu;
    C += (long)blockIdx.z * sCu;
    const int tm = blockIdx.x * 128;
    const int tn = blockIdx.y * 128;
    __shared__ __attribute__((aligned(16))) f16 As[128 * 32];
    __shared__ __attribute__((aligned(16))) f16 Ws[128 * 32];
    const int tid  = threadIdx.x;
    const int wave = tid >> 6;
    const int lane = tid & 63;
    const int wm = (wave >> 1) * 64;
    const int wn = (wave & 1) * 64;
    const int r16 = lane >> 2;        // row within 16-row staging group
    const int c8  = (lane & 3) * 8;   // k chunk (8 halves = 16B)
    const int mrow = lane & 15;
    const int kq   = (lane >> 4) * 8;

    f32x4 acc[4][4] = {};

    for (int kk = 0; kk < K; kk += 32) {
        __syncthreads();
#pragma unroll
        for (int t = 0; t < 2; t++) {
            const int rbase = wave * 16 + t * 64;   // wave-uniform LDS base; HW: base + lane*16
            async16(A + (long)(tm + rbase + r16) * lda + (kk + c8), &As[rbase * 32]);
            async16(W + (long)(tn + rbase + r16) * K   + (kk + c8), &Ws[rbase * 32]);
        }
        __syncthreads();
        f16x8 aF[4], wF[4];
#pragma unroll
        for (int i = 0; i < 4; i++)
            aF[i] = *(const f16x8*)&As[(wm + i * 16 + mrow) * 32 + kq];
#pragma unroll
        for (int j = 0; j < 4; j++)
            wF[j] = *(const f16x8*)&Ws[(wn + j * 16 + mrow) * 32 + kq];
#pragma unroll
        for (int i = 0; i < 4; i++)
#pragma unroll
            for (int j = 0; j < 4; j++)
                acc[i][j] = __builtin_amdgcn_mfma_f32_16x16x32_f16(aF[i], wF[j], acc[i][j], 0, 0, 0);
    }
    const int rrow = (lane >> 4) * 4;   // C/D: col = lane&15, row = (lane>>4)*4 + r
#pragma unroll
    for (int i = 0; i < 4; i++)
#pragma unroll
        for (int j = 0; j < 4; j++)
#pragma unroll
            for (int r = 0; r < 4; r++)
                C[(long)(tm + wm + i * 16 + rrow + r) * ldc + (tn + wn + j * 16 + mrow)] = acc[i][j][r];
}

// ---------------- fp32 GEMM, N=64 fixed (top-k-critical path) -----------------
// C[M,64] = A[M,K] @ W[K,64].  M%64==0.
__global__ __launch_bounds__(256)
void sgemm_n64(const float* __restrict__ A, const float* __restrict__ W,
               float* __restrict__ C, int K, int lda, int ldc,
               long sAu, long sWu, long sCu)
{
    A += (long)blockIdx.z * sAu;
    W += (long)blockIdx.z * sWu;
    C += (long)blockIdx.z * sCu;
    const int tm = blockIdx.x * 64;
    __shared__ __attribute__((aligned(16))) float As[64 * 9];   // pad 8->9 vs bank conflicts
    __shared__ __attribute__((aligned(16))) float Ws[8 * 64];
    const int t = threadIdx.x;
    const int tx = t & 15, ty = t >> 4;
    float acc[4][4] = {{0.f}};
    for (int kk = 0; kk < K; kk += 8) {
        __syncthreads();
#pragma unroll
        for (int i = 0; i < 2; i++) {
            const int idx = t + i * 256;
            const int m = idx >> 3, k = idx & 7;
            As[m * 9 + k] = (kk + k < K) ? A[(long)(tm + m) * lda + kk + k] : 0.f;
            const int kw = idx >> 6, n = idx & 63;
            Ws[kw * 64 + n] = (kk + kw < K) ? W[(long)(kk + kw) * 64 + n] : 0.f;
        }
        __syncthreads();
#pragma unroll
        for (int kb = 0; kb < 8; kb++) {
            const float a0 = As[(ty * 4 + 0) * 9 + kb];
            const float a1 = As[(ty * 4 + 1) * 9 + kb];
            const float a2 = As[(ty * 4 + 2) * 9 + kb];
            const float a3 = As[(ty * 4 + 3) * 9 + kb];
            const f32x4 bv = *(const f32x4*)&Ws[kb * 64 + tx * 4];
#pragma unroll
            for (int c = 0; c < 4; c++) {
                acc[0][c] += a0 * bv[c];
                acc[1][c] += a1 * bv[c];
                acc[2][c] += a2 * bv[c];
                acc[3][c] += a3 * bv[c];
            }
        }
    }
#pragma unroll
    for (int r = 0; r < 4; r++)
#pragma unroll
        for (int c = 0; c < 4; c++)
            C[(long)(tm + ty * 4 + r) * ldc + tx * 4 + c] = acc[r][c];
}

// ---------------- weight transpose+convert: dst[n*ldd + k] = (f16)src[k*N + n] --
__global__ __launch_bounds__(256)
void wtrans(const float* __restrict__ src, f16* __restrict__ dst,
            int K, int N, int ldd, long sSrc, long sDst)
{
    src += (long)blockIdx.z * sSrc;
    dst += (long)blockIdx.z * sDst;
    __shared__ float tile[32][33];
    const int tK = blockIdx.x * 32, tN = blockIdx.y * 32;
    const int tx = threadIdx.x & 31, ty = threadIdx.x >> 5;
#pragma unroll
    for (int i = 0; i < 4; i++) {
        const int k = tK + ty + i * 8, n = tN + tx;
        if (k < K && n < N) tile[ty + i * 8][tx] = src[(long)k * N + n];
    }
    __syncthreads();
#pragma unroll
    for (int i = 0; i < 4; i++) {
        const int n = tN + ty + i * 8, k = tK + tx;
        if (n < N && k < K) dst[(long)n * ldd + k] = (f16)tile[tx][ty + i * 8];
    }
}

// ---------------- elementwise kernels -----------------------------------------
__global__ void xconv_kernel(const float* __restrict__ x, f16* __restrict__ xf, long n)
{
    const long i = (long)blockIdx.x * 256 + threadIdx.x;
    if (i >= n) return;
    const long b = i / 608;
    const int c = (int)(i - b * 608);
    xf[i] = (f16)(c < 600 ? x[b * 600 + c] : 0.f);
}

__global__ void s0_kernel(const float* __restrict__ q, const float* __restrict__ kx,
                          float* __restrict__ s0, int n)   // n = Bc*6; q (b,u,64), kx (b,64)
{
    const int i = blockIdx.x * 256 + threadIdx.x;
    if (i >= n) return;
    const int b = i / 6;
    const float* qp = q + (long)i * 64;
    const float* kp = kx + (long)b * 64;
    float s = 0.f;
#pragma unroll
    for (int k = 0; k < 64; k++) s += qp[k] * kp[k];
    s0[i] = s * 0.125f;    // / sqrt(64)
}

__global__ void mask_kernel(const float* __restrict__ s0, float* __restrict__ mask,
                            float* __restrict__ alpha, int Bc)
{
    const int b = blockIdx.x * 256 + threadIdx.x;
    if (b >= Bc) return;
    float v[6];
#pragma unroll
    for (int u = 0; u < 6; u++) v[u] = s0[b * 6 + u];
#pragma unroll
    for (int u = 0; u < 6; u++) {
        int rank = 0;
#pragma unroll
        for (int m = 0; m < 6; m++)
            rank += ((v[m] > v[u]) || (v[m] == v[u] && m < u)) ? 1 : 0;   // stable top-k
        const float mk = (rank < 4) ? 1.f : 0.f;
        mask[b * 6 + u] = mk;
        alpha[b * 6 + u] = mk / (1.f + __expf(-v[u]));   // sigmoid(s0)*mask (softmax vs zero-key)
    }
}

__global__ void inputs_kernel(const float* __restrict__ vx, const float* __restrict__ hs,
                              const float* __restrict__ alpha, f16* __restrict__ icat, long n)
{   // icat (b,u,1024) = [alpha*vx(400) | hs(600) | 0(24)]
    const long i = (long)blockIdx.x * 256 + threadIdx.x;
    if (i >= n) return;
    const int k = (int)(i & 1023);
    const long bu = i >> 10;
    float v;
    if (k < 400)       v = alpha[bu] * vx[(bu / 6) * 512 + k];
    else if (k < 1000) v = hs[bu * 600 + (k - 400)];
    else               v = 0.f;
    icat[i] = (f16)v;
}

__device__ __forceinline__ float tanh_fast(float x) {
    x = fminf(20.f, fmaxf(-20.f, x));
    const float e = __expf(2.f * x);
    return (e - 1.f) / (e + 1.f);
}

__global__ void lstm_kernel(const float* __restrict__ pre, const float* __restrict__ cs,
                            const float* __restrict__ mask, float* __restrict__ cs_out,
                            f16* __restrict__ hbf, long n)   // n = Bc*6*608
{
    const long i = (long)blockIdx.x * 256 + threadIdx.x;
    if (i >= n) return;
    const long bu = i / 608;
    const int h = (int)(i - bu * 608);
    if (h >= 600) { hbf[i] = (f16)0.f; return; }   // zero K-pad for next GEMM
    const float* p = pre + bu * 2432;
    const float ig = 1.f / (1.f + __expf(-p[h]));
    const float fg = 1.f / (1.f + __expf(-p[600 + h]));
    const float og = 1.f / (1.f + __expf(-p[1200 + h]));
    const float g  = tanh_fast(p[1800 + h]);
    const float cold = cs[bu * 600 + h];
    const float c = cold * fg + ig * g;
    cs_out[bu * 600 + h] = (mask[bu] != 0.f) ? c : cold;
    hbf[i] = (f16)(og * tanh_fast(c));
}

__global__ __launch_bounds__(256)
void attn_kernel(const float* __restrict__ out2, const float* __restrict__ mask,
                 f16* __restrict__ ctx)
{   // out2 (b,m,2688): [cv 0:2400 | ck 2400:2528 | cq 2528:2656 | pad]
    const long b = blockIdx.x;
    __shared__ float sck[6][128];
    __shared__ float scq[6][128];
    __shared__ float sp[4][6][6];
    const int t = threadIdx.x;
#pragma unroll
    for (int m = 0; m < 6; m++) {
        const float* row = out2 + (b * 6 + m) * 2688;
        if (t < 128) sck[m][t] = row[2400 + t];
        else         scq[m][t - 128] = row[2528 + (t - 128)];
    }
    __syncthreads();
    if (t < 144) {                         // (h,u,m) scores
        const int h = t / 36, u = (t / 6) % 6, m = t % 6;
        float s = 0.f;
#pragma unroll
        for (int k = 0; k < 32; k++) s += scq[u][h * 32 + k] * sck[m][h * 32 + k];
        sp[h][u][m] = s * 0.1767766952966369f;   // 1/sqrt(32)
    }
    __syncthreads();
    if (t < 24) {                          // softmax over m, then * mask[u]
        const int h = t / 6, u = t % 6;
        float mx = sp[h][u][0];
#pragma unroll
        for (int m = 1; m < 6; m++) mx = fmaxf(mx, sp[h][u][m]);
        float e[6], sum = 0.f;
#pragma unroll
        for (int m = 0; m < 6; m++) { e[m] = __expf(sp[h][u][m] - mx); sum += e[m]; }
        const float sc = mask[b * 6 + u] / sum;
#pragma unroll
        for (int m = 0; m < 6; m++) sp[h][u][m] = e[m] * sc;
    }
    __syncthreads();
    for (int f = t; f < 2400; f += 256) {  // ctx[b,u,f] = sum_m p[h(f),u,m]*cv[b,m,f]
        const int h = f / 600;
        float cv[6];
#pragma unroll
        for (int m = 0; m < 6; m++) cv[m] = out2[(b * 6 + m) * 2688 + f];
#pragma unroll
        for (int u = 0; u < 6; u++) {
            float s = 0.f;
#pragma unroll
            for (int m = 0; m < 6; m++) s += sp[h][u][m] * cv[m];
            ctx[(b * 6 + u) * 2400 + f] = (f16)s;
        }
    }
}

__global__ void epi_kernel(const float* __restrict__ ctxW, const f16* __restrict__ hbf,
                           const float* __restrict__ hs, const float* __restrict__ mask,
                           float* __restrict__ hs_out, long n)   // n = Bc*3600
{
    const long i = (long)blockIdx.x * 256 + threadIdx.x;
    if (i >= n) return;
    const long bu = i / 600;
    const int h = (int)(i - bu * 600);
    hs_out[i] = (mask[bu] != 0.f) ? (ctxW[bu * 640 + h] + (float)hbf[bu * 608 + h]) : hs[i];
}

// ---------------- host launcher ------------------------------------------------
static inline unsigned cdivu(long a, long b) { return (unsigned)((a + b - 1) / b); }

extern "C" void kernel_launch(void* const* d_in, const int* in_sizes, int n_in,
                              void* d_out, int out_size, void* d_ws, size_t ws_size,
                              hipStream_t stream)
{
    (void)in_sizes; (void)n_in; (void)out_size;
    const float* x    = (const float*)d_in[0];
    const float* hs   = (const float*)d_in[1];
    const float* cs   = (const float*)d_in[2];
    const float* Wk   = (const float*)d_in[3];
    const float* Wv   = (const float*)d_in[4];
    const float* Wq   = (const float*)d_in[5];
    const float* Wi2h = (const float*)d_in[6];
    const float* Wh2h = (const float*)d_in[7];
    const float* Wck  = (const float*)d_in[8];
    const float* Wcq  = (const float*)d_in[9];
    const float* Wcv  = (const float*)d_in[10];
    const float* Wco  = (const float*)d_in[11];
    float* hs_out = (float*)d_out;
    float* cs_out = hs_out + (long)4096 * 6 * 600;

    char* wsb = (char*)d_ws;
    size_t off = 0;
    auto alloc = [&](size_t bytes) -> char* {
        char* p = wsb + off;
        off += (bytes + 255) & ~(size_t)255;
        return p;
    };

    // f16 weights, transposed to (N,K), padded: W1T (2432,1024) [Wi2h;Wh2h],
    // W2T (2688,608) [Wcv|Wck|Wcq], W3T (640,2400) [Wco], WvT (512,608) [Wv]
    f16* W1T = (f16*)alloc((size_t)6 * 2432 * 1024 * 2);
    f16* W2T = (f16*)alloc((size_t)6 * 2688 * 608 * 2);
    f16* W3T = (f16*)alloc((size_t)6 * 640 * 2400 * 2);
    f16* WvT = (f16*)alloc((size_t)512 * 608 * 2);
    const size_t wbytes = off;

    // pick batch chunk so activations fit the workspace
    int Bc = 4096;
    const size_t perRow = 147616;   // bytes of activation workspace per batch row
    while (Bc > 128 && wbytes + (size_t)Bc * perRow + 16384 > ws_size) Bc >>= 1;

    f16*   xf   = (f16*)  alloc((size_t)Bc * 608 * 2);
    float* kx   = (float*)alloc((size_t)Bc * 64 * 4);
    float* vx   = (float*)alloc((size_t)Bc * 512 * 4);
    float* q    = (float*)alloc((size_t)Bc * 6 * 64 * 4);
    float* s0   = (float*)alloc((size_t)Bc * 6 * 4);
    float* alph = (float*)alloc((size_t)Bc * 6 * 4);
    float* mskv = (float*)alloc((size_t)Bc * 6 * 4);
    f16*   icat = (f16*)  alloc((size_t)Bc * 6 * 1024 * 2);
    float* pre  = (float*)alloc((size_t)Bc * 6 * 2432 * 4);
    f16*   hbf  = (f16*)  alloc((size_t)Bc * 6 * 608 * 2);
    float* out2 = (float*)alloc((size_t)Bc * 6 * 2688 * 4);
    // ctx / ctxW overlay the dead preact buffer (consumed by LSTM before attention)
    f16*   ctx  = (f16*)pre;
    float* ctxW = (float*)((char*)pre + (((size_t)Bc * 6 * 2400 * 2 + 255) & ~(size_t)255));

    // ---- weights: zero pads, then transpose-convert ----
    hipMemsetAsync(d_ws, 0, wbytes, stream);
    wtrans<<<dim3(13, 75, 6), 256, 0, stream>>>(Wi2h, W1T,        400, 2400, 1024, 960000L,  2490368L);
    wtrans<<<dim3(19, 75, 6), 256, 0, stream>>>(Wh2h, W1T + 400,  600, 2400, 1024, 1440000L, 2490368L);
    wtrans<<<dim3(19, 75, 6), 256, 0, stream>>>(Wcv,  W2T,        600, 2400, 608,  1440000L, 1634304L);
    wtrans<<<dim3(19, 4, 6),  256, 0, stream>>>(Wck,  W2T + (long)2400 * 608, 600, 128, 608, 76800L, 1634304L);
    wtrans<<<dim3(19, 4, 6),  256, 0, stream>>>(Wcq,  W2T + (long)2528 * 608, 600, 128, 608, 76800L, 1634304L);
    wtrans<<<dim3(75, 19, 6), 256, 0, stream>>>(Wco,  W3T,        2400, 600, 2400, 1440000L, 1536000L);
    wtrans<<<dim3(19, 13, 1), 256, 0, stream>>>(Wv,   WvT,        600,  400, 608,  0L, 0L);

    for (int b0 = 0; b0 < 4096; b0 += Bc) {
        const float* xc  = x  + (long)b0 * 600;
        const float* hsc = hs + (long)b0 * 3600;
        const float* csc = cs + (long)b0 * 3600;
        float* hso = hs_out + (long)b0 * 3600;
        float* cso = cs_out + (long)b0 * 3600;

        xconv_kernel<<<cdivu((long)Bc * 608, 256), 256, 0, stream>>>(xc, xf, (long)Bc * 608);
        // fp32 (top-k critical): kx = x@Wk ; q = hs@Wq per unit
        sgemm_n64<<<dim3(Bc / 64, 1, 1), 256, 0, stream>>>(xc,  Wk, kx, 600, 600,  64,  0,   0,     0);
        sgemm_n64<<<dim3(Bc / 64, 1, 6), 256, 0, stream>>>(hsc, Wq, q,  600, 3600, 384, 600, 38400, 64);
        // vx = x@Wv (f16 MFMA)
        mfma_gemm<<<dim3(Bc / 128, 4, 1), 256, 0, stream>>>(xf, WvT, vx, 608, 608, 512, 0, 0, 0);
        s0_kernel<<<cdivu((long)Bc * 6, 256), 256, 0, stream>>>(q, kx, s0, Bc * 6);
        mask_kernel<<<cdivu(Bc, 256), 256, 0, stream>>>(s0, mskv, alph, Bc);
        inputs_kernel<<<cdivu((long)Bc * 6144, 256), 256, 0, stream>>>(vx, hsc, alph, icat, (long)Bc * 6144);
        // preact = [a*vx|hs] @ [Wi2h;Wh2h]
        mfma_gemm<<<dim3(Bc / 128, 19, 6), 256, 0, stream>>>(icat, W1T, pre, 1024, 6144, 14592, 1024, 2490368, 2432);
        lstm_kernel<<<cdivu((long)Bc * 3648, 256), 256, 0, stream>>>(pre, csc, mskv, cso, hbf, (long)Bc * 3648);
        // [cv|ck|cq] = h @ [Wcv|Wck|Wcq]
        mfma_gemm<<<dim3(Bc / 128, 21, 6), 256, 0, stream>>>(hbf, W2T, out2, 608, 3648, 16128, 608, 1634304, 2688);
        attn_kernel<<<Bc, 256, 0, stream>>>(out2, mskv, ctx);
        // ctxW = ctx @ Wco
        mfma_gemm<<<dim3(Bc / 128, 5, 6), 256, 0, stream>>>(ctx, W3T, ctxW, 2400, 14400, 3840, 2400, 1536000, 640);
        epi_kernel<<<cdivu((long)Bc * 3600, 256), 256, 0, stream>>>(ctxW, hbf, hsc, mskv, hso, (long)Bc * 3600);
    }
}

// Round 2
// 1201.269 us; speedup vs baseline: 1.3699x; 1.3699x over previous
//
#include <hip/hip_runtime.h>
#include <cstdint>
#include <cstddef>

// RIMCell forward, MI355X.
//  Full-batch: wtrans (weights->f16 (N,K)), xconv, fused fp32 q/kx GEMM (top-k
//  critical -> exact fp32), vx = x@Wv (f16 MFMA), s0, mask/alpha.
//  Chunked (ws-limited): inputs build, preact GEMM, LSTM, comm GEMM, attention,
//  ctx@Wco GEMM, epilogue.
// Output d_out = [hs_out (B,6,600) | cs_out (B,6,600)] fp32.

typedef _Float16 f16;
typedef _Float16 f16x8 __attribute__((ext_vector_type(8)));
typedef float    f32x4 __attribute__((ext_vector_type(4)));

__device__ __forceinline__ void async16(const void* g, void* l) {
    __builtin_amdgcn_global_load_lds((const __attribute__((address_space(1))) void*)g,
                                     (__attribute__((address_space(3))) void*)l,
                                     16, 0, 0);
}

// ---------------- MFMA f16 GEMM: C[M,N] = A[M,K] * W^T where W stored (N,K) ----
// M%128==0 (grid.x=M/128), N%128==0 (grid.y=N/128), K%32==0. W row pitch == K.
__global__ __launch_bounds__(256)
void mfma_gemm(const f16* __restrict__ A, const f16* __restrict__ W,
               float* __restrict__ C, int K, int lda, int ldc,
               long sAu, long sWu, long sCu)
{
    A += (long)blockIdx.z * sAu;
    W += (long)blockIdx.z * sWu;
    C += (long)blockIdx.z * sCu;
    const int tm = blockIdx.x * 128;
    const int tn = blockIdx.y * 128;
    __shared__ __attribute__((aligned(16))) f16 As[128 * 32];
    __shared__ __attribute__((aligned(16))) f16 Ws[128 * 32];
    const int tid  = threadIdx.x;
    const int wave = tid >> 6;
    const int lane = tid & 63;
    const int wm = (wave >> 1) * 64;
    const int wn = (wave & 1) * 64;
    const int r16 = lane >> 2;        // row within 16-row staging group
    const int c8  = (lane & 3) * 8;   // k chunk (8 halves = 16B)
    const int mrow = lane & 15;
    const int kq   = (lane >> 4) * 8;

    f32x4 acc[4][4] = {};

    for (int kk = 0; kk < K; kk += 32) {
        __syncthreads();
#pragma unroll
        for (int t = 0; t < 2; t++) {
            const int rbase = wave * 16 + t * 64;   // wave-uniform LDS base; HW: base + lane*16
            async16(A + (long)(tm + rbase + r16) * lda + (kk + c8), &As[rbase * 32]);
            async16(W + (long)(tn + rbase + r16) * K   + (kk + c8), &Ws[rbase * 32]);
        }
        __syncthreads();
        f16x8 aF[4], wF[4];
#pragma unroll
        for (int i = 0; i < 4; i++)
            aF[i] = *(const f16x8*)&As[(wm + i * 16 + mrow) * 32 + kq];
#pragma unroll
        for (int j = 0; j < 4; j++)
            wF[j] = *(const f16x8*)&Ws[(wn + j * 16 + mrow) * 32 + kq];
#pragma unroll
        for (int i = 0; i < 4; i++)
#pragma unroll
            for (int j = 0; j < 4; j++)
                acc[i][j] = __builtin_amdgcn_mfma_f32_16x16x32_f16(aF[i], wF[j], acc[i][j], 0, 0, 0);
    }
    const int rrow = (lane >> 4) * 4;   // C/D: col = lane&15, row = (lane>>4)*4 + r
#pragma unroll
    for (int i = 0; i < 4; i++)
#pragma unroll
        for (int j = 0; j < 4; j++)
#pragma unroll
            for (int r = 0; r < 4; r++)
                C[(long)(tm + wm + i * 16 + rrow + r) * ldc + (tn + wn + j * 16 + mrow)] = acc[i][j][r];
}

// ---------------- fused fp32 GEMM (top-k critical): q = hs@Wq (z<6), kx = x@Wk (z==6)
// M=4096, N=64, K=600. Tile M=64, K-step 16, register-prefetch pipeline.
__global__ __launch_bounds__(256)
void sgemm_fused(const float* __restrict__ hs, const float* __restrict__ Wq,
                 const float* __restrict__ x, const float* __restrict__ Wk,
                 float* __restrict__ q, float* __restrict__ kx)
{
    const int z = blockIdx.z;
    const float* A; const float* W; float* C; int lda, ldc;
    if (z < 6) { A = hs + z * 600; W = Wq + (long)z * 38400; C = q + z * 64; lda = 3600; ldc = 384; }
    else       { A = x;            W = Wk;                   C = kx;         lda = 600;  ldc = 64;  }
    const int K = 600;
    const int tm = blockIdx.x * 64;
    __shared__ __attribute__((aligned(16))) float AsT[16][64];   // k-major
    __shared__ __attribute__((aligned(16))) float Ws[16][64];
    const int t = threadIdx.x;
    const int arow = t >> 2, akc = (t & 3) * 4;   // A staging: row, k-chunk
    const int wkw = t >> 4, wn = (t & 15) * 4;    // W staging
    const int tx = t & 15, ty = t >> 4;           // compute: 4 cols, 4 rows per thread

    float4 aR, wR;
    const float* Arow = A + (long)(tm + arow) * lda;
    auto loadA = [&](int kk) {
        const int k0 = kk + akc;
        const float* p = Arow + k0;
        if (k0 + 3 < K) aR = *(const float4*)p;
        else {
            aR.x = (k0 + 0 < K) ? p[0] : 0.f; aR.y = (k0 + 1 < K) ? p[1] : 0.f;
            aR.z = (k0 + 2 < K) ? p[2] : 0.f; aR.w = (k0 + 3 < K) ? p[3] : 0.f;
        }
    };
    auto loadW = [&](int kk) {
        const int k = kk + wkw;
        if (k < K) wR = *(const float4*)(W + (long)k * 64 + wn);
        else       wR = float4{0.f, 0.f, 0.f, 0.f};
    };
    loadA(0); loadW(0);
    float acc[4][4] = {{0.f}};
    const int NS = 38;   // ceil(600/16)
    for (int s = 0; s < NS; s++) {
        __syncthreads();
        AsT[akc + 0][arow] = aR.x; AsT[akc + 1][arow] = aR.y;
        AsT[akc + 2][arow] = aR.z; AsT[akc + 3][arow] = aR.w;
        *(float4*)&Ws[wkw][wn] = wR;
        __syncthreads();
        if (s + 1 < NS) { loadA((s + 1) * 16); loadW((s + 1) * 16); }   // overlap w/ compute
#pragma unroll
        for (int k = 0; k < 16; k++) {
            const float4 av = *(const float4*)&AsT[k][ty * 4];   // broadcast reads
            const float4 wv = *(const float4*)&Ws[k][tx * 4];
            acc[0][0] += av.x * wv.x; acc[0][1] += av.x * wv.y; acc[0][2] += av.x * wv.z; acc[0][3] += av.x * wv.w;
            acc[1][0] += av.y * wv.x; acc[1][1] += av.y * wv.y; acc[1][2] += av.y * wv.z; acc[1][3] += av.y * wv.w;
            acc[2][0] += av.z * wv.x; acc[2][1] += av.z * wv.y; acc[2][2] += av.z * wv.z; acc[2][3] += av.z * wv.w;
            acc[3][0] += av.w * wv.x; acc[3][1] += av.w * wv.y; acc[3][2] += av.w * wv.z; acc[3][3] += av.w * wv.w;
        }
    }
#pragma unroll
    for (int r = 0; r < 4; r++)
#pragma unroll
        for (int c = 0; c < 4; c++)
            C[(long)(tm + ty * 4 + r) * ldc + tx * 4 + c] = acc[r][c];
}

// ---------------- weight transpose+convert: dst[n*ldd + k] = (f16)src[k*N + n] --
__global__ __launch_bounds__(256)
void wtrans(const float* __restrict__ src, f16* __restrict__ dst,
            int K, int N, int ldd, long sSrc, long sDst)
{
    src += (long)blockIdx.z * sSrc;
    dst += (long)blockIdx.z * sDst;
    __shared__ float tile[32][33];
    const int tK = blockIdx.x * 32, tN = blockIdx.y * 32;
    const int tx = threadIdx.x & 31, ty = threadIdx.x >> 5;
#pragma unroll
    for (int i = 0; i < 4; i++) {
        const int k = tK + ty + i * 8, n = tN + tx;
        if (k < K && n < N) tile[ty + i * 8][tx] = src[(long)k * N + n];
    }
    __syncthreads();
#pragma unroll
    for (int i = 0; i < 4; i++) {
        const int n = tN + ty + i * 8, k = tK + tx;
        if (n < N && k < K) dst[(long)n * ldd + k] = (f16)tile[tx][ty + i * 8];
    }
}

// ---------------- elementwise kernels -----------------------------------------
__global__ void xconv_kernel(const float* __restrict__ x, f16* __restrict__ xf, long n)
{
    const long i = (long)blockIdx.x * 256 + threadIdx.x;
    if (i >= n) return;
    const long b = i / 608;
    const int c = (int)(i - b * 608);
    xf[i] = (f16)(c < 600 ? x[b * 600 + c] : 0.f);
}

__global__ void s0_kernel(const float* __restrict__ q, const float* __restrict__ kx,
                          float* __restrict__ s0, int n)   // n = B*6; q (b,u,64), kx (b,64)
{
    const int i = blockIdx.x * 256 + threadIdx.x;
    if (i >= n) return;
    const int b = i / 6;
    const float* qp = q + (long)i * 64;
    const float* kp = kx + (long)b * 64;
    float s = 0.f;
#pragma unroll
    for (int k = 0; k < 64; k++) s += qp[k] * kp[k];
    s0[i] = s * 0.125f;    // / sqrt(64)
}

__global__ void mask_kernel(const float* __restrict__ s0, float* __restrict__ mask,
                            float* __restrict__ alpha, int Bc)
{
    const int b = blockIdx.x * 256 + threadIdx.x;
    if (b >= Bc) return;
    float v[6];
#pragma unroll
    for (int u = 0; u < 6; u++) v[u] = s0[b * 6 + u];
#pragma unroll
    for (int u = 0; u < 6; u++) {
        int rank = 0;
#pragma unroll
        for (int m = 0; m < 6; m++)
            rank += ((v[m] > v[u]) || (v[m] == v[u] && m < u)) ? 1 : 0;   // stable top-k
        const float mk = (rank < 4) ? 1.f : 0.f;
        mask[b * 6 + u] = mk;
        alpha[b * 6 + u] = mk / (1.f + __expf(-v[u]));   // sigmoid(s0)*mask (softmax vs zero-key)
    }
}

__global__ void inputs_kernel(const float* __restrict__ vx, const float* __restrict__ hs,
                              const float* __restrict__ alpha, f16* __restrict__ icat, long n)
{   // icat (b,u,1024) = [alpha*vx(400) | hs(600) | 0(24)]
    const long i = (long)blockIdx.x * 256 + threadIdx.x;
    if (i >= n) return;
    const int k = (int)(i & 1023);
    const long bu = i >> 10;
    float v;
    if (k < 400)       v = alpha[bu] * vx[(bu / 6) * 512 + k];
    else if (k < 1000) v = hs[bu * 600 + (k - 400)];
    else               v = 0.f;
    icat[i] = (f16)v;
}

__device__ __forceinline__ float tanh_fast(float x) {
    x = fminf(20.f, fmaxf(-20.f, x));
    const float e = __expf(2.f * x);
    return (e - 1.f) / (e + 1.f);
}

__global__ void lstm_kernel(const float* __restrict__ pre, const float* __restrict__ cs,
                            const float* __restrict__ mask, float* __restrict__ cs_out,
                            f16* __restrict__ hbf, long n)   // n = Bc*6*608
{
    const long i = (long)blockIdx.x * 256 + threadIdx.x;
    if (i >= n) return;
    const long bu = i / 608;
    const int h = (int)(i - bu * 608);
    if (h >= 600) { hbf[i] = (f16)0.f; return; }   // zero K-pad for next GEMM
    const float* p = pre + bu * 2432;
    const float ig = 1.f / (1.f + __expf(-p[h]));
    const float fg = 1.f / (1.f + __expf(-p[600 + h]));
    const float og = 1.f / (1.f + __expf(-p[1200 + h]));
    const float g  = tanh_fast(p[1800 + h]);
    const float cold = cs[bu * 600 + h];
    const float c = cold * fg + ig * g;
    cs_out[bu * 600 + h] = (mask[bu] != 0.f) ? c : cold;
    hbf[i] = (f16)(og * tanh_fast(c));
}

__global__ __launch_bounds__(256)
void attn_kernel(const float* __restrict__ out2, const float* __restrict__ mask,
                 f16* __restrict__ ctx)
{   // out2 (b,m,2688): [cv 0:2400 | ck 2400:2528 | cq 2528:2656 | pad]
    const long b = blockIdx.x;
    __shared__ float sck[6][128];
    __shared__ float scq[6][128];
    __shared__ float sp[4][6][6];
    const int t = threadIdx.x;
#pragma unroll
    for (int m = 0; m < 6; m++) {
        const float* row = out2 + (b * 6 + m) * 2688;
        if (t < 128) sck[m][t] = row[2400 + t];
        else         scq[m][t - 128] = row[2528 + (t - 128)];
    }
    __syncthreads();
    if (t < 144) {                         // (h,u,m) scores
        const int h = t / 36, u = (t / 6) % 6, m = t % 6;
        float s = 0.f;
#pragma unroll
        for (int k = 0; k < 32; k++) s += scq[u][h * 32 + k] * sck[m][h * 32 + k];
        sp[h][u][m] = s * 0.1767766952966369f;   // 1/sqrt(32)
    }
    __syncthreads();
    if (t < 24) {                          // softmax over m, then * mask[u]
        const int h = t / 6, u = t % 6;
        float mx = sp[h][u][0];
#pragma unroll
        for (int m = 1; m < 6; m++) mx = fmaxf(mx, sp[h][u][m]);
        float e[6], sum = 0.f;
#pragma unroll
        for (int m = 0; m < 6; m++) { e[m] = __expf(sp[h][u][m] - mx); sum += e[m]; }
        const float sc = mask[b * 6 + u] / sum;
#pragma unroll
        for (int m = 0; m < 6; m++) sp[h][u][m] = e[m] * sc;
    }
    __syncthreads();
    for (int f = t; f < 2400; f += 256) {  // ctx[b,u,f] = sum_m p[h(f),u,m]*cv[b,m,f]
        const int h = f / 600;
        float cv[6];
#pragma unroll
        for (int m = 0; m < 6; m++) cv[m] = out2[(b * 6 + m) * 2688 + f];
#pragma unroll
        for (int u = 0; u < 6; u++) {
            float s = 0.f;
#pragma unroll
            for (int m = 0; m < 6; m++) s += sp[h][u][m] * cv[m];
            ctx[(b * 6 + u) * 2400 + f] = (f16)s;
        }
    }
}

__global__ void epi_kernel(const float* __restrict__ ctxW, const f16* __restrict__ hbf,
                           const float* __restrict__ hs, const float* __restrict__ mask,
                           float* __restrict__ hs_out, long n)   // n = Bc*3600
{
    const long i = (long)blockIdx.x * 256 + threadIdx.x;
    if (i >= n) return;
    const long bu = i / 600;
    const int h = (int)(i - bu * 600);
    hs_out[i] = (mask[bu] != 0.f) ? (ctxW[bu * 640 + h] + (float)hbf[bu * 608 + h]) : hs[i];
}

// ---------------- host launcher ------------------------------------------------
static inline unsigned cdivu(long a, long b) { return (unsigned)((a + b - 1) / b); }

extern "C" void kernel_launch(void* const* d_in, const int* in_sizes, int n_in,
                              void* d_out, int out_size, void* d_ws, size_t ws_size,
                              hipStream_t stream)
{
    (void)in_sizes; (void)n_in; (void)out_size;
    const float* x    = (const float*)d_in[0];
    const float* hs   = (const float*)d_in[1];
    const float* cs   = (const float*)d_in[2];
    const float* Wk   = (const float*)d_in[3];
    const float* Wv   = (const float*)d_in[4];
    const float* Wq   = (const float*)d_in[5];
    const float* Wi2h = (const float*)d_in[6];
    const float* Wh2h = (const float*)d_in[7];
    const float* Wck  = (const float*)d_in[8];
    const float* Wcq  = (const float*)d_in[9];
    const float* Wcv  = (const float*)d_in[10];
    const float* Wco  = (const float*)d_in[11];
    float* hs_out = (float*)d_out;
    float* cs_out = hs_out + (long)4096 * 6 * 600;

    char* wsb = (char*)d_ws;
    size_t off = 0;
    auto alloc = [&](size_t bytes) -> char* {
        char* p = wsb + off;
        off += (bytes + 255) & ~(size_t)255;
        return p;
    };

    // f16 weights, transposed to (N,K), padded: W1T (2432,1024) [Wi2h;Wh2h],
    // W2T (2688,608) [Wcv|Wck|Wcq], W3T (640,2400) [Wco], WvT (512,608) [Wv]
    f16* W1T = (f16*)alloc((size_t)6 * 2432 * 1024 * 2);
    f16* W2T = (f16*)alloc((size_t)6 * 2688 * 608 * 2);
    f16* W3T = (f16*)alloc((size_t)6 * 640 * 2400 * 2);
    f16* WvT = (f16*)alloc((size_t)512 * 608 * 2);
    const size_t wbytes = off;

    // full-batch buffers (B=4096)
    f16*   xf   = (f16*)  alloc((size_t)4096 * 608 * 2);
    float* kx   = (float*)alloc((size_t)4096 * 64 * 4);
    float* vx   = (float*)alloc((size_t)4096 * 512 * 4);
    float* q    = (float*)alloc((size_t)4096 * 384 * 4);
    float* s0   = (float*)alloc((size_t)4096 * 6 * 4);
    float* alph = (float*)alloc((size_t)4096 * 6 * 4);
    float* mskv = (float*)alloc((size_t)4096 * 6 * 4);
    const size_t fixedbytes = off;

    // pick batch chunk so per-chunk activations fit the workspace
    // perRow = icat 12288 + pre 58368 + hbf 7296 + out2 64512 = 142464 B
    const size_t perRow = 142464;
    int Bc = 4096;
    while (Bc > 128 && fixedbytes + (size_t)Bc * perRow + 16384 > ws_size) Bc >>= 1;

    f16*   icat = (f16*)  alloc((size_t)Bc * 6 * 1024 * 2);
    float* pre  = (float*)alloc((size_t)Bc * 6 * 2432 * 4);
    f16*   hbf  = (f16*)  alloc((size_t)Bc * 6 * 608 * 2);
    float* out2 = (float*)alloc((size_t)Bc * 6 * 2688 * 4);
    // ctx / ctxW overlay the dead preact buffer (consumed by LSTM before attention)
    f16*   ctx  = (f16*)pre;
    float* ctxW = (float*)((char*)pre + (((size_t)Bc * 6 * 2400 * 2 + 255) & ~(size_t)255));

    // ---- weights: zero pads, then transpose-convert ----
    hipMemsetAsync(d_ws, 0, wbytes, stream);
    wtrans<<<dim3(13, 75, 6), 256, 0, stream>>>(Wi2h, W1T,        400, 2400, 1024, 960000L,  2490368L);
    wtrans<<<dim3(19, 75, 6), 256, 0, stream>>>(Wh2h, W1T + 400,  600, 2400, 1024, 1440000L, 2490368L);
    wtrans<<<dim3(19, 75, 6), 256, 0, stream>>>(Wcv,  W2T,        600, 2400, 608,  1440000L, 1634304L);
    wtrans<<<dim3(19, 4, 6),  256, 0, stream>>>(Wck,  W2T + (long)2400 * 608, 600, 128, 608, 76800L, 1634304L);
    wtrans<<<dim3(19, 4, 6),  256, 0, stream>>>(Wcq,  W2T + (long)2528 * 608, 600, 128, 608, 76800L, 1634304L);
    wtrans<<<dim3(75, 19, 6), 256, 0, stream>>>(Wco,  W3T,        2400, 600, 2400, 1440000L, 1536000L);
    wtrans<<<dim3(19, 13, 1), 256, 0, stream>>>(Wv,   WvT,        600,  400, 608,  0L, 0L);

    // ---- full-batch score path (exact fp32 where top-k depends on it) ----
    xconv_kernel<<<cdivu((long)4096 * 608, 256), 256, 0, stream>>>(x, xf, (long)4096 * 608);
    sgemm_fused<<<dim3(64, 1, 7), 256, 0, stream>>>(hs, Wq, x, Wk, q, kx);
    mfma_gemm<<<dim3(32, 4, 1), 256, 0, stream>>>(xf, WvT, vx, 608, 608, 512, 0, 0, 0);
    s0_kernel<<<cdivu((long)4096 * 6, 256), 256, 0, stream>>>(q, kx, s0, 4096 * 6);
    mask_kernel<<<cdivu(4096, 256), 256, 0, stream>>>(s0, mskv, alph, 4096);

    for (int b0 = 0; b0 < 4096; b0 += Bc) {
        const float* hsc = hs + (long)b0 * 3600;
        const float* csc = cs + (long)b0 * 3600;
        float* hso = hs_out + (long)b0 * 3600;
        float* cso = cs_out + (long)b0 * 3600;

        inputs_kernel<<<cdivu((long)Bc * 6144, 256), 256, 0, stream>>>(
            vx + (long)b0 * 512, hsc, alph + (long)b0 * 6, icat, (long)Bc * 6144);
        // preact = [a*vx|hs] @ [Wi2h;Wh2h]
        mfma_gemm<<<dim3(Bc / 128, 19, 6), 256, 0, stream>>>(icat, W1T, pre, 1024, 6144, 14592, 1024, 2490368, 2432);
        lstm_kernel<<<cdivu((long)Bc * 3648, 256), 256, 0, stream>>>(
            pre, csc, mskv + (long)b0 * 6, cso, hbf, (long)Bc * 3648);
        // [cv|ck|cq] = h @ [Wcv|Wck|Wcq]
        mfma_gemm<<<dim3(Bc / 128, 21, 6), 256, 0, stream>>>(hbf, W2T, out2, 608, 3648, 16128, 608, 1634304, 2688);
        attn_kernel<<<Bc, 256, 0, stream>>>(out2, mskv + (long)b0 * 6, ctx);
        // ctxW = ctx @ Wco
        mfma_gemm<<<dim3(Bc / 128, 5, 6), 256, 0, stream>>>(ctx, W3T, ctxW, 2400, 14400, 3840, 2400, 1536000, 640);
        epi_kernel<<<cdivu((long)Bc * 3600, 256), 256, 0, stream>>>(
            ctxW, hbf, hsc, mskv + (long)b0 * 6, hso, (long)Bc * 3600);
    }
}

// Round 3
// 1111.117 us; speedup vs baseline: 1.4811x; 1.0811x over previous
//
#include <hip/hip_runtime.h>
#include <cstdint>
#include <cstddef>

// RIMCell forward, MI355X.
//  Full-batch: wtrans (weights->f16 (N,K), self-padding), xconv, fused fp32 q/kx
//  GEMM (top-k critical -> exact fp32), vx = x@Wv (f16 MFMA), s0, mask/alpha.
//  Then (single chunk if ws allows): inputs build, preact GEMM (f16 out), LSTM,
//  comm GEMM (f16 out), attention, ctx@Wco GEMM (f16 out), epilogue.
// Output d_out = [hs_out (B,6,600) | cs_out (B,6,600)] fp32.

typedef _Float16 f16;
typedef _Float16 f16x8 __attribute__((ext_vector_type(8)));
typedef float    f32x4 __attribute__((ext_vector_type(4)));

__device__ __forceinline__ void async16(const void* g, void* l) {
    __builtin_amdgcn_global_load_lds((const __attribute__((address_space(1))) void*)g,
                                     (__attribute__((address_space(3))) void*)l,
                                     16, 0, 0);
}

// ---------------- MFMA f16 GEMM: C[M,N] = A[M,K] * W^T where W stored (N,K) ----
// M%128==0 (grid.x=M/128), N%128==0 (grid.y=N/128), K%32==0. W row pitch == K.
template <typename CT>
__global__ __launch_bounds__(256)
void mfma_gemm(const f16* __restrict__ A, const f16* __restrict__ W,
               CT* __restrict__ C, int K, int lda, int ldc,
               long sAu, long sWu, long sCu)
{
    A += (long)blockIdx.z * sAu;
    W += (long)blockIdx.z * sWu;
    C += (long)blockIdx.z * sCu;
    const int tm = blockIdx.x * 128;
    const int tn = blockIdx.y * 128;
    __shared__ __attribute__((aligned(16))) f16 As[128 * 32];
    __shared__ __attribute__((aligned(16))) f16 Ws[128 * 32];
    const int tid  = threadIdx.x;
    const int wave = tid >> 6;
    const int lane = tid & 63;
    const int wm = (wave >> 1) * 64;
    const int wn = (wave & 1) * 64;
    const int r16 = lane >> 2;        // row within 16-row staging group
    const int c8  = (lane & 3) * 8;   // k chunk (8 halves = 16B)
    const int mrow = lane & 15;
    const int kq   = (lane >> 4) * 8;

    f32x4 acc[4][4] = {};

    for (int kk = 0; kk < K; kk += 32) {
        __syncthreads();
#pragma unroll
        for (int t = 0; t < 2; t++) {
            const int rbase = wave * 16 + t * 64;   // wave-uniform LDS base; HW: base + lane*16
            async16(A + (long)(tm + rbase + r16) * lda + (kk + c8), &As[rbase * 32]);
            async16(W + (long)(tn + rbase + r16) * K   + (kk + c8), &Ws[rbase * 32]);
        }
        __syncthreads();
        f16x8 aF[4], wF[4];
#pragma unroll
        for (int i = 0; i < 4; i++)
            aF[i] = *(const f16x8*)&As[(wm + i * 16 + mrow) * 32 + kq];
#pragma unroll
        for (int j = 0; j < 4; j++)
            wF[j] = *(const f16x8*)&Ws[(wn + j * 16 + mrow) * 32 + kq];
#pragma unroll
        for (int i = 0; i < 4; i++)
#pragma unroll
            for (int j = 0; j < 4; j++)
                acc[i][j] = __builtin_amdgcn_mfma_f32_16x16x32_f16(aF[i], wF[j], acc[i][j], 0, 0, 0);
    }
    const int rrow = (lane >> 4) * 4;   // C/D: col = lane&15, row = (lane>>4)*4 + r
#pragma unroll
    for (int i = 0; i < 4; i++)
#pragma unroll
        for (int j = 0; j < 4; j++)
#pragma unroll
            for (int r = 0; r < 4; r++)
                C[(long)(tm + wm + i * 16 + rrow + r) * ldc + (tn + wn + j * 16 + mrow)] = (CT)acc[i][j][r];
}

// ---------------- fused fp32 GEMM (top-k critical): q = hs@Wq (z<6), kx = x@Wk (z==6)
// M=4096, N=64, K=600. Tile M=64, K-step 16, register-prefetch pipeline.
__global__ __launch_bounds__(256)
void sgemm_fused(const float* __restrict__ hs, const float* __restrict__ Wq,
                 const float* __restrict__ x, const float* __restrict__ Wk,
                 float* __restrict__ q, float* __restrict__ kx)
{
    const int z = blockIdx.z;
    const float* A; const float* W; float* C; int lda, ldc;
    if (z < 6) { A = hs + z * 600; W = Wq + (long)z * 38400; C = q + z * 64; lda = 3600; ldc = 384; }
    else       { A = x;            W = Wk;                   C = kx;         lda = 600;  ldc = 64;  }
    const int K = 600;
    const int tm = blockIdx.x * 64;
    __shared__ __attribute__((aligned(16))) float AsT[16][64];   // k-major
    __shared__ __attribute__((aligned(16))) float Ws[16][64];
    const int t = threadIdx.x;
    const int arow = t >> 2, akc = (t & 3) * 4;   // A staging: row, k-chunk
    const int wkw = t >> 4, wn = (t & 15) * 4;    // W staging
    const int tx = t & 15, ty = t >> 4;           // compute: 4 cols, 4 rows per thread

    float4 aR, wR;
    const float* Arow = A + (long)(tm + arow) * lda;
    auto loadA = [&](int kk) {
        const int k0 = kk + akc;
        const float* p = Arow + k0;
        if (k0 + 3 < K) aR = *(const float4*)p;
        else {
            aR.x = (k0 + 0 < K) ? p[0] : 0.f; aR.y = (k0 + 1 < K) ? p[1] : 0.f;
            aR.z = (k0 + 2 < K) ? p[2] : 0.f; aR.w = (k0 + 3 < K) ? p[3] : 0.f;
        }
    };
    auto loadW = [&](int kk) {
        const int k = kk + wkw;
        if (k < K) wR = *(const float4*)(W + (long)k * 64 + wn);
        else       wR = float4{0.f, 0.f, 0.f, 0.f};
    };
    loadA(0); loadW(0);
    float acc[4][4] = {{0.f}};
    const int NS = 38;   // ceil(600/16)
    for (int s = 0; s < NS; s++) {
        __syncthreads();
        AsT[akc + 0][arow] = aR.x; AsT[akc + 1][arow] = aR.y;
        AsT[akc + 2][arow] = aR.z; AsT[akc + 3][arow] = aR.w;
        *(float4*)&Ws[wkw][wn] = wR;
        __syncthreads();
        if (s + 1 < NS) { loadA((s + 1) * 16); loadW((s + 1) * 16); }   // overlap w/ compute
#pragma unroll
        for (int k = 0; k < 16; k++) {
            const float4 av = *(const float4*)&AsT[k][ty * 4];   // broadcast reads
            const float4 wv = *(const float4*)&Ws[k][tx * 4];
            acc[0][0] += av.x * wv.x; acc[0][1] += av.x * wv.y; acc[0][2] += av.x * wv.z; acc[0][3] += av.x * wv.w;
            acc[1][0] += av.y * wv.x; acc[1][1] += av.y * wv.y; acc[1][2] += av.y * wv.z; acc[1][3] += av.y * wv.w;
            acc[2][0] += av.z * wv.x; acc[2][1] += av.z * wv.y; acc[2][2] += av.z * wv.z; acc[2][3] += av.z * wv.w;
            acc[3][0] += av.w * wv.x; acc[3][1] += av.w * wv.y; acc[3][2] += av.w * wv.z; acc[3][3] += av.w * wv.w;
        }
    }
#pragma unroll
    for (int r = 0; r < 4; r++)
#pragma unroll
        for (int c = 0; c < 4; c++)
            C[(long)(tm + ty * 4 + r) * ldc + tx * 4 + c] = acc[r][c];
}

// -------- weight transpose+convert with self-padding:
// dst[n*ldd + k] = (f16)src[k*N + n] for k<K,n<N; 0 for K<=k<Kp or N<=n<Np.
__global__ __launch_bounds__(256)
void wtrans(const float* __restrict__ src, f16* __restrict__ dst,
            int K, int N, int Kp, int Np, int ldd, long sSrc, long sDst)
{
    src += (long)blockIdx.z * sSrc;
    dst += (long)blockIdx.z * sDst;
    __shared__ float tile[32][33];
    const int tK = blockIdx.x * 32, tN = blockIdx.y * 32;
    const int tx = threadIdx.x & 31, ty = threadIdx.x >> 5;
#pragma unroll
    for (int i = 0; i < 4; i++) {
        const int k = tK + ty + i * 8, n = tN + tx;
        tile[ty + i * 8][tx] = (k < K && n < N) ? src[(long)k * N + n] : 0.f;
    }
    __syncthreads();
#pragma unroll
    for (int i = 0; i < 4; i++) {
        const int n = tN + ty + i * 8, k = tK + tx;
        if (n < Np && k < Kp) dst[(long)n * ldd + k] = (f16)tile[tx][ty + i * 8];
    }
}

// ---------------- elementwise kernels -----------------------------------------
__global__ void xconv_kernel(const float* __restrict__ x, f16* __restrict__ xf, long n)
{
    const long i = (long)blockIdx.x * 256 + threadIdx.x;
    if (i >= n) return;
    const long b = i / 608;
    const int c = (int)(i - b * 608);
    xf[i] = (f16)(c < 600 ? x[b * 600 + c] : 0.f);
}

__global__ void s0_kernel(const float* __restrict__ q, const float* __restrict__ kx,
                          float* __restrict__ s0, int n)   // n = B*6; q (b,u,64), kx (b,64)
{
    const int i = blockIdx.x * 256 + threadIdx.x;
    if (i >= n) return;
    const int b = i / 6;
    const float* qp = q + (long)i * 64;
    const float* kp = kx + (long)b * 64;
    float s = 0.f;
#pragma unroll
    for (int k = 0; k < 64; k++) s += qp[k] * kp[k];
    s0[i] = s * 0.125f;    // / sqrt(64)
}

__global__ void mask_kernel(const float* __restrict__ s0, float* __restrict__ mask,
                            float* __restrict__ alpha, int Bc)
{
    const int b = blockIdx.x * 256 + threadIdx.x;
    if (b >= Bc) return;
    float v[6];
#pragma unroll
    for (int u = 0; u < 6; u++) v[u] = s0[b * 6 + u];
#pragma unroll
    for (int u = 0; u < 6; u++) {
        int rank = 0;
#pragma unroll
        for (int m = 0; m < 6; m++)
            rank += ((v[m] > v[u]) || (v[m] == v[u] && m < u)) ? 1 : 0;   // stable top-k
        const float mk = (rank < 4) ? 1.f : 0.f;
        mask[b * 6 + u] = mk;
        alpha[b * 6 + u] = mk / (1.f + __expf(-v[u]));   // sigmoid(s0)*mask (softmax vs zero-key)
    }
}

__global__ void inputs_kernel(const float* __restrict__ vx, const float* __restrict__ hs,
                              const float* __restrict__ alpha, f16* __restrict__ icat, long n)
{   // icat (b,u,1024) = [alpha*vx(400) | hs(600) | 0(24)]
    const long i = (long)blockIdx.x * 256 + threadIdx.x;
    if (i >= n) return;
    const int k = (int)(i & 1023);
    const long bu = i >> 10;
    float v;
    if (k < 400)       v = alpha[bu] * vx[(bu / 6) * 512 + k];
    else if (k < 1000) v = hs[bu * 600 + (k - 400)];
    else               v = 0.f;
    icat[i] = (f16)v;
}

__device__ __forceinline__ float tanh_fast(float x) {
    x = fminf(20.f, fmaxf(-20.f, x));
    const float e = __expf(2.f * x);
    return (e - 1.f) / (e + 1.f);
}

__global__ void lstm_kernel(const f16* __restrict__ pre, const float* __restrict__ cs,
                            const float* __restrict__ mask, float* __restrict__ cs_out,
                            f16* __restrict__ hbf, long n)   // n = Bc*6*608
{
    const long i = (long)blockIdx.x * 256 + threadIdx.x;
    if (i >= n) return;
    const long bu = i / 608;
    const int h = (int)(i - bu * 608);
    if (h >= 600) { hbf[i] = (f16)0.f; return; }   // zero K-pad for next GEMM
    const f16* p = pre + bu * 2432;
    const float ig = 1.f / (1.f + __expf(-(float)p[h]));
    const float fg = 1.f / (1.f + __expf(-(float)p[600 + h]));
    const float og = 1.f / (1.f + __expf(-(float)p[1200 + h]));
    const float g  = tanh_fast((float)p[1800 + h]);
    const float cold = cs[bu * 600 + h];
    const float c = cold * fg + ig * g;
    cs_out[bu * 600 + h] = (mask[bu] != 0.f) ? c : cold;
    hbf[i] = (f16)(og * tanh_fast(c));
}

__global__ __launch_bounds__(256)
void attn_kernel(const f16* __restrict__ out2, const float* __restrict__ mask,
                 f16* __restrict__ ctx)
{   // out2 (b,m,2688) f16: [cv 0:2400 | ck 2400:2528 | cq 2528:2656 | pad]
    const long b = blockIdx.x;
    __shared__ float sck[6][128];
    __shared__ float scq[6][128];
    __shared__ float sp[4][6][6];
    const int t = threadIdx.x;
#pragma unroll
    for (int m = 0; m < 6; m++) {
        const f16* row = out2 + (b * 6 + m) * 2688;
        if (t < 128) sck[m][t] = (float)row[2400 + t];
        else         scq[m][t - 128] = (float)row[2528 + (t - 128)];
    }
    __syncthreads();
    if (t < 144) {                         // (h,u,m) scores
        const int h = t / 36, u = (t / 6) % 6, m = t % 6;
        float s = 0.f;
#pragma unroll
        for (int k = 0; k < 32; k++) s += scq[u][h * 32 + k] * sck[m][h * 32 + k];
        sp[h][u][m] = s * 0.1767766952966369f;   // 1/sqrt(32)
    }
    __syncthreads();
    if (t < 24) {                          // softmax over m, then * mask[u]
        const int h = t / 6, u = t % 6;
        float mx = sp[h][u][0];
#pragma unroll
        for (int m = 1; m < 6; m++) mx = fmaxf(mx, sp[h][u][m]);
        float e[6], sum = 0.f;
#pragma unroll
        for (int m = 0; m < 6; m++) { e[m] = __expf(sp[h][u][m] - mx); sum += e[m]; }
        const float sc = mask[b * 6 + u] / sum;
#pragma unroll
        for (int m = 0; m < 6; m++) sp[h][u][m] = e[m] * sc;
    }
    __syncthreads();
    for (int f = t; f < 2400; f += 256) {  // ctx[b,u,f] = sum_m p[h(f),u,m]*cv[b,m,f]
        const int h = f / 600;
        float cv[6];
#pragma unroll
        for (int m = 0; m < 6; m++) cv[m] = (float)out2[(b * 6 + m) * 2688 + f];
#pragma unroll
        for (int u = 0; u < 6; u++) {
            float s = 0.f;
#pragma unroll
            for (int m = 0; m < 6; m++) s += sp[h][u][m] * cv[m];
            ctx[(b * 6 + u) * 2400 + f] = (f16)s;
        }
    }
}

__global__ void epi_kernel(const f16* __restrict__ ctxW, const f16* __restrict__ hbf,
                           const float* __restrict__ hs, const float* __restrict__ mask,
                           float* __restrict__ hs_out, long n)   // n = Bc*3600
{
    const long i = (long)blockIdx.x * 256 + threadIdx.x;
    if (i >= n) return;
    const long bu = i / 600;
    const int h = (int)(i - bu * 600);
    hs_out[i] = (mask[bu] != 0.f) ? ((float)ctxW[bu * 640 + h] + (float)hbf[bu * 608 + h]) : hs[i];
}

// ---------------- host launcher ------------------------------------------------
static inline unsigned cdivu(long a, long b) { return (unsigned)((a + b - 1) / b); }

extern "C" void kernel_launch(void* const* d_in, const int* in_sizes, int n_in,
                              void* d_out, int out_size, void* d_ws, size_t ws_size,
                              hipStream_t stream)
{
    (void)in_sizes; (void)n_in; (void)out_size;
    const float* x    = (const float*)d_in[0];
    const float* hs   = (const float*)d_in[1];
    const float* cs   = (const float*)d_in[2];
    const float* Wk   = (const float*)d_in[3];
    const float* Wv   = (const float*)d_in[4];
    const float* Wq   = (const float*)d_in[5];
    const float* Wi2h = (const float*)d_in[6];
    const float* Wh2h = (const float*)d_in[7];
    const float* Wck  = (const float*)d_in[8];
    const float* Wcq  = (const float*)d_in[9];
    const float* Wcv  = (const float*)d_in[10];
    const float* Wco  = (const float*)d_in[11];
    float* hs_out = (float*)d_out;
    float* cs_out = hs_out + (long)4096 * 6 * 600;

    char* wsb = (char*)d_ws;
    size_t off = 0;
    auto alloc = [&](size_t bytes) -> char* {
        char* p = wsb + off;
        off += (bytes + 255) & ~(size_t)255;
        return p;
    };

    // f16 weights, transposed to (N,K), padded: W1T (2432,1024) [Wi2h;Wh2h],
    // W2T (2688,608) [Wcv|Wck|Wcq], W3T (640,2400) [Wco], WvT (512,608) [Wv]
    f16* W1T = (f16*)alloc((size_t)6 * 2432 * 1024 * 2);
    f16* W2T = (f16*)alloc((size_t)6 * 2688 * 608 * 2);
    f16* W3T = (f16*)alloc((size_t)6 * 640 * 2400 * 2);
    f16* WvT = (f16*)alloc((size_t)512 * 608 * 2);

    // full-batch buffers (B=4096)
    f16*   xf   = (f16*)  alloc((size_t)4096 * 608 * 2);
    float* kx   = (float*)alloc((size_t)4096 * 64 * 4);
    float* vx   = (float*)alloc((size_t)4096 * 512 * 4);
    float* q    = (float*)alloc((size_t)4096 * 384 * 4);
    float* s0   = (float*)alloc((size_t)4096 * 6 * 4);
    float* alph = (float*)alloc((size_t)4096 * 6 * 4);
    float* mskv = (float*)alloc((size_t)4096 * 6 * 4);
    const size_t fixedbytes = off;

    // per-chunk activations (all f16 now):
    // perRow = icat 12288 + pre 29184 + hbf 7296 + out2 32256 = 81024 B
    const size_t perRow = 81024;
    int Bc = 4096;
    while (Bc > 128 && fixedbytes + (size_t)Bc * perRow + 16384 > ws_size) Bc >>= 1;

    f16* icat = (f16*)alloc((size_t)Bc * 6 * 1024 * 2);
    f16* pre  = (f16*)alloc((size_t)Bc * 6 * 2432 * 2);
    f16* hbf  = (f16*)alloc((size_t)Bc * 6 * 608 * 2);
    f16* out2 = (f16*)alloc((size_t)Bc * 6 * 2688 * 2);
    // overlays: ctx over dead pre (after LSTM); ctxW over dead out2 (after attn)
    f16* ctx  = pre;    // needs Bc*6*2400*2 <= Bc*6*2432*2  ok
    f16* ctxW = out2;   // needs Bc*6*640*2  <= Bc*6*2688*2  ok

    // ---- weights: transpose-convert with self-padding (no memset needed) ----
    wtrans<<<dim3(13, 76, 6), 256, 0, stream>>>(Wi2h, W1T,        400, 2400, 400, 2432, 1024, 960000L,  2490368L);
    wtrans<<<dim3(20, 76, 6), 256, 0, stream>>>(Wh2h, W1T + 400,  600, 2400, 624, 2432, 1024, 1440000L, 2490368L);
    wtrans<<<dim3(19, 75, 6), 256, 0, stream>>>(Wcv,  W2T,        600, 2400, 608, 2400, 608,  1440000L, 1634304L);
    wtrans<<<dim3(19, 4, 6),  256, 0, stream>>>(Wck,  W2T + (long)2400 * 608, 600, 128, 608, 128, 608, 76800L, 1634304L);
    wtrans<<<dim3(19, 5, 6),  256, 0, stream>>>(Wcq,  W2T + (long)2528 * 608, 600, 128, 608, 160, 608, 76800L, 1634304L);
    wtrans<<<dim3(75, 20, 6), 256, 0, stream>>>(Wco,  W3T,        2400, 600, 2400, 640, 2400, 1440000L, 1536000L);
    wtrans<<<dim3(19, 16, 1), 256, 0, stream>>>(Wv,   WvT,        600,  400, 608, 512, 608,  0L, 0L);

    // ---- full-batch score path (exact fp32 where top-k depends on it) ----
    xconv_kernel<<<cdivu((long)4096 * 608, 256), 256, 0, stream>>>(x, xf, (long)4096 * 608);
    sgemm_fused<<<dim3(64, 1, 7), 256, 0, stream>>>(hs, Wq, x, Wk, q, kx);
    mfma_gemm<float><<<dim3(32, 4, 1), 256, 0, stream>>>(xf, WvT, vx, 608, 608, 512, 0, 0, 0);
    s0_kernel<<<cdivu((long)4096 * 6, 256), 256, 0, stream>>>(q, kx, s0, 4096 * 6);
    mask_kernel<<<cdivu(4096, 256), 256, 0, stream>>>(s0, mskv, alph, 4096);

    for (int b0 = 0; b0 < 4096; b0 += Bc) {
        const float* hsc = hs + (long)b0 * 3600;
        const float* csc = cs + (long)b0 * 3600;
        float* hso = hs_out + (long)b0 * 3600;
        float* cso = cs_out + (long)b0 * 3600;

        inputs_kernel<<<cdivu((long)Bc * 6144, 256), 256, 0, stream>>>(
            vx + (long)b0 * 512, hsc, alph + (long)b0 * 6, icat, (long)Bc * 6144);
        // preact = [a*vx|hs] @ [Wi2h;Wh2h]   (f16 out)
        mfma_gemm<f16><<<dim3(Bc / 128, 19, 6), 256, 0, stream>>>(icat, W1T, pre, 1024, 6144, 14592, 1024, 2490368, 2432);
        lstm_kernel<<<cdivu((long)Bc * 3648, 256), 256, 0, stream>>>(
            pre, csc, mskv + (long)b0 * 6, cso, hbf, (long)Bc * 3648);
        // [cv|ck|cq] = h @ [Wcv|Wck|Wcq]   (f16 out)
        mfma_gemm<f16><<<dim3(Bc / 128, 21, 6), 256, 0, stream>>>(hbf, W2T, out2, 608, 3648, 16128, 608, 1634304, 2688);
        attn_kernel<<<Bc, 256, 0, stream>>>(out2, mskv + (long)b0 * 6, ctx);
        // ctxW = ctx @ Wco   (f16 out)
        mfma_gemm<f16><<<dim3(Bc / 128, 5, 6), 256, 0, stream>>>(ctx, W3T, ctxW, 2400, 14400, 3840, 2400, 1536000, 640);
        epi_kernel<<<cdivu((long)Bc * 3600, 256), 256, 0, stream>>>(
            ctxW, hbf, hsc, mskv + (long)b0 * 6, hso, (long)Bc * 3600);
    }
}